// Round 16
// baseline (239.347 us; speedup 1.0000x reference)
//
#include <hip/hip_runtime.h>
#include <hip/hip_bf16.h>

#define M 8192
#define N 8192
#define K 512
#define BM 128
#define BN 128
#define BK 32
#define NSTEP 16  // K-steps per tile
#define NTILE 4   // col tiles per block

typedef __attribute__((ext_vector_type(8))) short bf16x8;
typedef __attribute__((ext_vector_type(4))) float f32x4;
typedef __attribute__((ext_vector_type(8))) unsigned short us8;

__device__ inline void gload_lds16(const void* g, void* l) {
  __builtin_amdgcn_global_load_lds(
      (const __attribute__((address_space(1))) unsigned int*)g,
      (__attribute__((address_space(3))) unsigned int*)l, 16, 0, 0);
}

// Pin VMEM issue order across this point (loads before drain stores).
#define MEMFENCE() asm volatile("" ::: "memory")

#define BARRIER()                          \
  do {                                     \
    asm volatile("" ::: "memory");         \
    __builtin_amdgcn_s_barrier();          \
    asm volatile("" ::: "memory");         \
  } while (0)

// Fused prep: cast f32 rows -> bf16, store INVERSE L2 norm (1/max(norm,1e-4)).
__global__ __launch_bounds__(256) void prep_kernel(const float* __restrict__ img,
                                                   const float* __restrict__ txt,
                                                   unsigned short* __restrict__ Abf,
                                                   unsigned short* __restrict__ Bbf,
                                                   float* __restrict__ w1,
                                                   float* __restrict__ w2) {
  const int half = blockIdx.x >> 11;
  const int lb = blockIdx.x & 2047;
  const float* in = half ? txt : img;
  unsigned short* outb = half ? Bbf : Abf;
  float* norms = half ? w2 : w1;

  const int gw = (lb * 256 + threadIdx.x) >> 6;
  const int lane = threadIdx.x & 63;
  const float4* rp4 = (const float4*)(in + (size_t)gw * K);
  float4 v0 = rp4[lane * 2];
  float4 v1 = rp4[lane * 2 + 1];
  float ss = v0.x * v0.x + v0.y * v0.y + v0.z * v0.z + v0.w * v0.w +
             v1.x * v1.x + v1.y * v1.y + v1.z * v1.z + v1.w * v1.w;
  float f[8] = {v0.x, v0.y, v0.z, v0.w, v1.x, v1.y, v1.z, v1.w};
  us8 o;
#pragma unroll
  for (int i = 0; i < 8; ++i) {
    __hip_bfloat16 b = __float2bfloat16(f[i]);
    o[i] = *(unsigned short*)&b;
  }
  *(us8*)(outb + (size_t)gw * K + lane * 8) = o;
#pragma unroll
  for (int off = 32; off > 0; off >>= 1) ss += __shfl_down(ss, off, 64);
  if (lane == 0) norms[gw] = 1.0f / fmaxf(sqrtf(ss), 1e-4f);
}

// Persistent drain-interleaved GEMM: 1024 blocks x 256 thr (4 waves, wave
// tile 64x64). Block owns a fixed 128-row strip, walks 4 col-tiles within
// its XCD's 8-panel window. Per K-step the previous tile's output drains
// one fragment (mul-only scaling) -> C-write stream overlaps compute.
// FIFO per step (fence-pinned): [A x2][B x2][st x4]; vmcnt(6) completes
// everything step g+1 needs, leaves B(g+2)+st(g) in flight (r6 discipline).
__global__ __launch_bounds__(256, 2) void gemm_kernel(const unsigned short* __restrict__ A,
                                                      const unsigned short* __restrict__ B,
                                                      const float* __restrict__ iw1,
                                                      const float* __restrict__ iw2,
                                                      float* __restrict__ C) {
  __shared__ __align__(128) unsigned short As[2][BM * BK];  // 2 x 8 KB
  __shared__ __align__(128) unsigned short Bs[3][BN * BK];  // 3 x 8 KB

  const int tid = threadIdx.x;
  const int wave = tid >> 6;  // 0..3
  const int lane = tid & 63;
  const int wr = wave >> 1;  // 0..1 : M strip of 64
  const int wc = wave & 1;   // 0..1 : N strip of 64
  const int fr = lane & 15;
  const int fq = lane >> 4;

  const int xcd = blockIdx.x & 7;
  const int idx = blockIdx.x >> 3;             // 0..127
  const int bRow = (idx >> 1) * BM;            // 64 row strips
  const int c0 = xcd * 8 + (idx & 1) * 4;      // 4-panel walk inside XCD window
  auto colOf = [&](int t) { return (c0 + t) * BN; };

  // Staging: 16 rows x 64B per wave per call; source granule pre-swizzled
  // so LDS slot j holds global granule j ^ ((row>>1)&3)  (rule #21, r9-proven).
  const int srow = lane >> 2;                               // 0..15
  const int scol = (((lane & 3) ^ ((srow >> 1) & 3)) * 8);  // bf16 offset

  auto stageA = [&](int buf, int sl) {
#pragma unroll
    for (int c = 0; c < 2; ++c)
      gload_lds16(A + (size_t)(bRow + c * 64 + wave * 16 + srow) * K + sl * BK + scol,
                  (char*)&As[buf][0] + (c * 64 + wave * 16) * 64);
  };
  auto stageB = [&](int buf, int bCol, int sl) {
#pragma unroll
    for (int c = 0; c < 2; ++c)
      gload_lds16(B + (size_t)(bCol + c * 64 + wave * 16 + srow) * K + sl * BK + scol,
                  (char*)&Bs[buf][0] + (c * 64 + wave * 16) * 64);
  };
  auto ldA = [&](int buf, int r) -> bf16x8 {
    return *(const bf16x8*)((const char*)&As[buf][0] + r * 64 + ((fq ^ ((r >> 1) & 3)) * 16));
  };
  auto ldB = [&](int buf, int r) -> bf16x8 {
    return *(const bf16x8*)((const char*)&Bs[buf][0] + r * 64 + ((fq ^ ((r >> 1) & 3)) * 16));
  };

  // Inverse row norms for this lane's 16 output rows (fixed per block).
  float i1v[4][4];
#pragma unroll
  for (int m = 0; m < 4; ++m)
#pragma unroll
    for (int r = 0; r < 4; ++r) i1v[m][r] = iw1[bRow + wr * 64 + m * 16 + fq * 4 + r];

  f32x4 accA[4][4] = {}, accB[4][4] = {};  // accB zeros feed tile0's fake drain
  float i2A[4] = {}, i2B[4] = {};

  // Prologue: A slice0, B(g=0), B(g=1). Need A0,B0 landed; B1 in flight.
  stageA(0, 0);
  stageB(0, colOf(0), 0);
  stageB(1, colOf(0), 1);
  asm volatile("s_waitcnt vmcnt(2)" ::: "memory");
  BARRIER();

  // One tile: accumulate `acc` (16 steps), drain one `prev` fragment/step.
  // Tile 0 fake-drains zeros to tile3 addrs (tail overwrites after vmcnt(0)).
  auto tile_body = [&](f32x4 (&acc)[4][4], float (&i2)[4],
                       f32x4 (&prev)[4][4], float (&i2p)[4], int t) {
    const int colCur = colOf(t);
    const int colPrev = (t == 0) ? colOf(3) : colOf(t - 1);
#pragma unroll
    for (int n = 0; n < 4; ++n) i2[n] = iw2[colCur + wc * 64 + n * 16 + fr];
#pragma unroll
    for (int m = 0; m < 4; ++m)
#pragma unroll
      for (int n = 0; n < 4; ++n) acc[m][n] = (f32x4){0.f, 0.f, 0.f, 0.f};

#pragma unroll
    for (int s = 0; s < NSTEP; ++s) {
      const int g = t * NSTEP + s;
      const int cur = s & 1, nxt = cur ^ 1;

      stageA(nxt, (s + 1) & 15);  // 2 gloads (A panel cycles k-slices)
      {
        const int g2 = (g + 2 > 63) ? 63 : (g + 2);  // clamp: uniform dummy FIFO
        stageB((g + 2) % 3, colOf(g2 >> 4), g2 & 15);  // 2 gloads
      }
      MEMFENCE();  // loads precede drain stores in the VMEM FIFO
      {
        const int dm = s >> 2, dn = s & 3;
        const int col = colPrev + wc * 64 + dn * 16 + fr;
        const int row0 = bRow + wr * 64 + dm * 16 + fq * 4;
#pragma unroll
        for (int r = 0; r < 4; ++r)
          C[(size_t)(row0 + r) * N + col] = prev[dm][dn][r] * i1v[dm][r] * i2p[dn];
      }

      bf16x8 a[4], b[4];
#pragma unroll
      for (int m = 0; m < 4; ++m) a[m] = ldA(cur, wr * 64 + m * 16 + fr);
      const int bc = g % 3;
#pragma unroll
      for (int n = 0; n < 4; ++n) b[n] = ldB(bc, wc * 64 + n * 16 + fr);

      __builtin_amdgcn_s_setprio(1);
#pragma unroll
      for (int m = 0; m < 4; ++m)
#pragma unroll
        for (int n = 0; n < 4; ++n)
          acc[m][n] = __builtin_amdgcn_mfma_f32_16x16x32_bf16(a[m], b[n], acc[m][n], 0, 0, 0);
      __builtin_amdgcn_s_setprio(0);

      // Queue: [B(g+1)x2][st(g-1)x4][A(g+1)x2][B(g+2)x2][st(g)x4] -> vmcnt(6)
      // completes B(g+1), st(g-1), A(g+1); leaves B(g+2)+st(g) in flight.
      asm volatile("s_waitcnt vmcnt(6)" ::: "memory");
      BARRIER();
    }
  };

#pragma clang loop unroll(disable)
  for (int p = 0; p < 2; ++p) {
    tile_body(accA, i2A, accB, i2B, 2 * p);
    tile_body(accB, i2B, accA, i2A, 2 * p + 1);
  }

  // Tail: all fakes/dummies retired, then drain tile3 (accB) for real.
  asm volatile("s_waitcnt vmcnt(0)" ::: "memory");
#pragma unroll
  for (int dm = 0; dm < 4; ++dm) {
    const int row0 = bRow + wr * 64 + dm * 16 + fq * 4;
#pragma unroll
    for (int dn = 0; dn < 4; ++dn) {
      const int col = colOf(3) + wc * 64 + dn * 16 + fr;
#pragma unroll
      for (int r = 0; r < 4; ++r)
        C[(size_t)(row0 + r) * N + col] = accB[dm][dn][r] * i1v[dm][r] * i2B[dn];
    }
  }
}

extern "C" void kernel_launch(void* const* d_in, const int* in_sizes, int n_in,
                              void* d_out, int out_size, void* d_ws, size_t ws_size,
                              hipStream_t stream) {
  (void)in_sizes; (void)n_in; (void)out_size; (void)ws_size;
  const float* img = (const float*)d_in[0];
  const float* txt = (const float*)d_in[1];
  float* out = (float*)d_out;

  unsigned short* Abf = (unsigned short*)d_ws;
  unsigned short* Bbf = Abf + (size_t)M * K;
  float* w1 = (float*)(Bbf + (size_t)N * K);
  float* w2 = w1 + M;

  prep_kernel<<<4096, 256, 0, stream>>>(img, txt, Abf, Bbf, w1, w2);
  gemm_kernel<<<1024, 256, 0, stream>>>(Abf, Bbf, w1, w2, out);
}

// Round 17
// 125.603 us; speedup vs baseline: 1.9056x; 1.9056x over previous
//
#include <hip/hip_runtime.h>
#include <hip/hip_bf16.h>

#define M 8192
#define N 8192
#define K 512
#define BM 128
#define BN 128
#define BK 32

typedef __attribute__((ext_vector_type(8))) short bf16x8;
typedef __attribute__((ext_vector_type(4))) float f32x4;
typedef __attribute__((ext_vector_type(8))) unsigned short us8;

__device__ inline void gload_lds16(const void* g, void* l) {
  __builtin_amdgcn_global_load_lds(
      (const __attribute__((address_space(1))) unsigned int*)g,
      (__attribute__((address_space(3))) unsigned int*)l, 16, 0, 0);
}

#define MEMFENCE() asm volatile("" ::: "memory")

#define BARRIER()                          \
  do {                                     \
    asm volatile("" ::: "memory");         \
    __builtin_amdgcn_s_barrier();          \
    asm volatile("" ::: "memory");         \
  } while (0)

// Fused prep: cast f32 rows -> bf16, store INVERSE L2 norm (1/max(norm,1e-4)).
__global__ __launch_bounds__(256) void prep_kernel(const float* __restrict__ img,
                                                   const float* __restrict__ txt,
                                                   unsigned short* __restrict__ Abf,
                                                   unsigned short* __restrict__ Bbf,
                                                   float* __restrict__ w1,
                                                   float* __restrict__ w2) {
  const int half = blockIdx.x >> 11;
  const int lb = blockIdx.x & 2047;
  const float* in = half ? txt : img;
  unsigned short* outb = half ? Bbf : Abf;
  float* norms = half ? w2 : w1;

  const int gw = (lb * 256 + threadIdx.x) >> 6;
  const int lane = threadIdx.x & 63;
  const float4* rp4 = (const float4*)(in + (size_t)gw * K);
  float4 v0 = rp4[lane * 2];
  float4 v1 = rp4[lane * 2 + 1];
  float ss = v0.x * v0.x + v0.y * v0.y + v0.z * v0.z + v0.w * v0.w +
             v1.x * v1.x + v1.y * v1.y + v1.z * v1.z + v1.w * v1.w;
  float f[8] = {v0.x, v0.y, v0.z, v0.w, v1.x, v1.y, v1.z, v1.w};
  us8 o;
#pragma unroll
  for (int i = 0; i < 8; ++i) {
    __hip_bfloat16 b = __float2bfloat16(f[i]);
    o[i] = *(unsigned short*)&b;
  }
  *(us8*)(outb + (size_t)gw * K + lane * 8) = o;
#pragma unroll
  for (int off = 32; off > 0; off >>= 1) ss += __shfl_down(ss, off, 64);
  if (lane == 0) norms[gw] = 1.0f / fmaxf(sqrtf(ss), 1e-4f);
}

// Two-tile async-epilogue GEMM: 2048 blocks x 256 thr (4 waves, 64x64 wave
// tiles). Each block: fixed 128-row strip, TWO adjacent col tiles (shared A
// panel). One seamless 32-step staging pipeline (r13 schedule). Tile0's
// epilogue drains during tile1's K-loop as 4 FULL-LINE chunks (16 stores =
// 16 rows x 256B contiguous each) -> C-write overlaps compute with zero
// partial-line RMW (r16's failure mechanism removed).
__global__ __launch_bounds__(256, 2) void gemm_kernel(const unsigned short* __restrict__ A,
                                                      const unsigned short* __restrict__ B,
                                                      const float* __restrict__ iw1,
                                                      const float* __restrict__ iw2,
                                                      float* __restrict__ C) {
  __shared__ __align__(128) unsigned short As[2][BM * BK];  // 2 x 8 KB
  __shared__ __align__(128) unsigned short Bs[3][BN * BK];  // 3 x 8 KB

  const int tid = threadIdx.x;
  const int wave = tid >> 6;  // 0..3
  const int lane = tid & 63;
  const int wr = wave >> 1;
  const int wc = wave & 1;
  const int fr = lane & 15;
  const int fq = lane >> 4;

  // xcd owns col-panels [xcd*8, xcd*8+8); idx>>2 walks 64 row strips,
  // idx&3 walks 4 col-pairs -> 8 blocks share each A panel (L2/L3-local).
  const int xcd = blockIdx.x & 7;
  const int idx = blockIdx.x >> 3;  // 0..255
  const int bRow = (idx >> 2) * BM;
  const int col0 = (xcd * 8 + (idx & 3) * 2) * BN;
  const int col1 = col0 + BN;

  // Staging (r9/r13-proven): 16 rows x 64B per wave per call; source granule
  // pre-swizzled so LDS slot j holds granule j ^ ((row>>1)&3) (rule #21).
  const int srow = lane >> 2;
  const int scol = (((lane & 3) ^ ((srow >> 1) & 3)) * 8);

  auto stageA = [&](int buf, int sl) {
#pragma unroll
    for (int c = 0; c < 2; ++c)
      gload_lds16(A + (size_t)(bRow + c * 64 + wave * 16 + srow) * K + sl * BK + scol,
                  (char*)&As[buf][0] + (c * 64 + wave * 16) * 64);
  };
  auto stageB = [&](int buf, int bCol, int sl) {
#pragma unroll
    for (int c = 0; c < 2; ++c)
      gload_lds16(B + (size_t)(bCol + c * 64 + wave * 16 + srow) * K + sl * BK + scol,
                  (char*)&Bs[buf][0] + (c * 64 + wave * 16) * 64);
  };
  auto ldA = [&](int buf, int r) -> bf16x8 {
    return *(const bf16x8*)((const char*)&As[buf][0] + r * 64 + ((fq ^ ((r >> 1) & 3)) * 16));
  };
  auto ldB = [&](int buf, int r) -> bf16x8 {
    return *(const bf16x8*)((const char*)&Bs[buf][0] + r * 64 + ((fq ^ ((r >> 1) & 3)) * 16));
  };

  // All norm loads issued BEFORE the staging pipeline (vmcnt queue stays pure).
  float i1v[4][4], i2v0[4], i2v1[4];
#pragma unroll
  for (int m = 0; m < 4; ++m)
#pragma unroll
    for (int r = 0; r < 4; ++r) i1v[m][r] = iw1[bRow + wr * 64 + m * 16 + fq * 4 + r];
#pragma unroll
  for (int n = 0; n < 4; ++n) {
    i2v0[n] = iw2[col0 + wc * 64 + n * 16 + fr];
    i2v1[n] = iw2[col1 + wc * 64 + n * 16 + fr];
  }

  f32x4 acc0[4][4] = {}, acc1[4][4] = {};

  // colOf for the 32-step superloop's B staging (clamped dummies past end).
  auto colOfStep = [&](int g) { return (g >> 4) ? col1 : col0; };

  // Prologue: A slice0, B(0), B(1). Norm loads + A0 + B0 done; B1 in flight.
  stageA(0, 0);
  stageB(0, col0, 0);
  stageB(1, col0, 1);
  asm volatile("s_waitcnt vmcnt(2)" ::: "memory");
  BARRIER();

  // Full-line drain chunk: one m-group of acc0 -> 16 rows x 256B contiguous.
  auto drain_chunk = [&](int mi) {
    const int row0 = bRow + wr * 64 + mi * 16 + fq * 4;
#pragma unroll
    for (int n = 0; n < 4; ++n) {
      const int col = col0 + wc * 64 + n * 16 + fr;
#pragma unroll
      for (int r = 0; r < 4; ++r)
        C[(size_t)(row0 + r) * N + col] = acc0[mi][n][r] * i1v[mi][r] * i2v0[n];
    }
  };

#define KSTEP(GG, ACC, DRAIN_MI, WAITN)                                          \
  do {                                                                           \
    const int cur = (GG) & 1, nxt = cur ^ 1;                                     \
    stageA(nxt, ((GG) + 1) & 15);                                                \
    {                                                                            \
      const int g2 = ((GG) + 2 > 31) ? 31 : ((GG) + 2); /* clamped dummy */      \
      stageB(((GG) + 2) % 3, colOfStep(g2), g2 & 15);                            \
    }                                                                            \
    MEMFENCE();                                                                  \
    if ((DRAIN_MI) >= 0) drain_chunk(DRAIN_MI);                                  \
    bf16x8 a[4], b[4];                                                           \
    _Pragma("unroll") for (int m = 0; m < 4; ++m)                                \
        a[m] = ldA(cur, wr * 64 + m * 16 + fr);                                  \
    const int bc = (GG) % 3;                                                     \
    _Pragma("unroll") for (int n = 0; n < 4; ++n)                                \
        b[n] = ldB(bc, wc * 64 + n * 16 + fr);                                   \
    __builtin_amdgcn_s_setprio(1);                                               \
    _Pragma("unroll") for (int m = 0; m < 4; ++m)                                \
        _Pragma("unroll") for (int n = 0; n < 4; ++n)                            \
            ACC[m][n] = __builtin_amdgcn_mfma_f32_16x16x32_bf16(                 \
                a[m], b[n], ACC[m][n], 0, 0, 0);                                 \
    __builtin_amdgcn_s_setprio(0);                                               \
    asm volatile("s_waitcnt vmcnt(" #WAITN ")" ::: "memory");                    \
    BARRIER();                                                                   \
  } while (0)

  // Tile 0: steps 0..15 (staging flows seamlessly into tile 1's panels).
#pragma unroll
  for (int s = 0; s < 16; ++s) KSTEP(s, acc0, -1, 2);

  // Tile 1: steps 16..31; acc0 drains in 4 full-line chunks at s=1,5,9,13.
  KSTEP(16, acc1, -1, 2);
  KSTEP(17, acc1, 0, 18);
  KSTEP(18, acc1, -1, 2);
  KSTEP(19, acc1, -1, 2);
  KSTEP(20, acc1, -1, 2);
  KSTEP(21, acc1, 1, 18);
  KSTEP(22, acc1, -1, 2);
  KSTEP(23, acc1, -1, 2);
  KSTEP(24, acc1, -1, 2);
  KSTEP(25, acc1, 2, 18);
  KSTEP(26, acc1, -1, 2);
  KSTEP(27, acc1, -1, 2);
  KSTEP(28, acc1, -1, 2);
  KSTEP(29, acc1, 3, 18);
  KSTEP(30, acc1, -1, 2);
  KSTEP(31, acc1, -1, 2);
#undef KSTEP

  // Tail: drain tile 1 (burst, full-line order: per-m row groups).
  asm volatile("s_waitcnt vmcnt(0)" ::: "memory");
#pragma unroll
  for (int mi = 0; mi < 4; ++mi) {
    const int row0 = bRow + wr * 64 + mi * 16 + fq * 4;
#pragma unroll
    for (int n = 0; n < 4; ++n) {
      const int col = col1 + wc * 64 + n * 16 + fr;
#pragma unroll
      for (int r = 0; r < 4; ++r)
        C[(size_t)(row0 + r) * N + col] = acc1[mi][n][r] * i1v[mi][r] * i2v1[n];
    }
  }
}

extern "C" void kernel_launch(void* const* d_in, const int* in_sizes, int n_in,
                              void* d_out, int out_size, void* d_ws, size_t ws_size,
                              hipStream_t stream) {
  (void)in_sizes; (void)n_in; (void)out_size; (void)ws_size;
  const float* img = (const float*)d_in[0];
  const float* txt = (const float*)d_in[1];
  float* out = (float*)d_out;

  unsigned short* Abf = (unsigned short*)d_ws;
  unsigned short* Bbf = Abf + (size_t)M * K;
  float* w1 = (float*)(Bbf + (size_t)N * K);
  float* w2 = w1 + M;

  prep_kernel<<<4096, 256, 0, stream>>>(img, txt, Abf, Bbf, w1, w2);
  gemm_kernel<<<2048, 256, 0, stream>>>(Abf, Bbf, w1, w2, out);
}